// Round 6
// baseline (272.259 us; speedup 1.0000x reference)
//
#include <hip/hip_runtime.h>

typedef unsigned int u32;
typedef unsigned short u16;
typedef unsigned long long u64;
typedef float f32x4 __attribute__((ext_vector_type(4)));
typedef u32 u32x4 __attribute__((ext_vector_type(4)));
typedef u32 u32x2 __attribute__((ext_vector_type(2)));

#define DEVINL static __device__ __forceinline__
#define LOG2E 1.44269504088896340736f
#define QSCALE 0.18033688011112042f /* 0.125 * LOG2E */

DEVINL u16 f2bf(float f) {
  u32 u = __builtin_bit_cast(u32, f);
  u32 r = u + 0x7FFFu + ((u >> 16) & 1u);
  return (u16)(r >> 16);
}

DEVINL u32 cvtpk(float lo, float hi) {
  u32 r;
  asm("v_cvt_pk_bf16_f32 %0, %1, %2" : "=v"(r) : "v"(lo), "v"(hi));
  return r;
}
DEVINL float exp2v(float x) {
  float r;
  asm("v_exp_f32 %0, %1" : "=v"(r) : "v"(x));
  return r;
}
DEVINL void mfma_b16(f32x4& c, u32x4 a, u32x4 b) {
  asm volatile("v_mfma_f32_16x16x32_bf16 %0, %1, %2, %0" : "+v"(c) : "v"(a), "v"(b));
}
DEVINL void mfma_fence() { asm volatile("s_nop 7\n\ts_nop 7"); }

DEVINL int mbcnt64(u64 m) {
  return __builtin_amdgcn_mbcnt_hi((u32)(m >> 32), __builtin_amdgcn_mbcnt_lo((u32)m, 0));
}
DEVINL u64 shfl_xor64(u64 v, int m) {
  u32 lo = (u32)v, hi = (u32)(v >> 32);
  lo = __shfl_xor(lo, m, 64);
  hi = __shfl_xor(hi, m, 64);
  return ((u64)hi << 32) | lo;
}

// ---------------------------------------------------------------------------
// prep: x -> bf16; tiled transpose of Wq/Wk/Wv -> WqkvT [1536][256] bf16 and
// Wo -> WoT [512][512] bf16; concat qkv bias. Grid = 1024 + 96 + 64 + 1.
// ---------------------------------------------------------------------------
__global__ __launch_bounds__(256) void prep_kernel(
    const float* __restrict__ x, const float* __restrict__ Wq, const float* __restrict__ Wk,
    const float* __restrict__ Wv, const float* __restrict__ Wo, const float* __restrict__ bq,
    const float* __restrict__ bk, const float* __restrict__ bv, u16* __restrict__ xb,
    u16* __restrict__ WqkvT, u16* __restrict__ WoT, float* __restrict__ biasQKV) {
  __shared__ float T[64][65];
  const int blk = blockIdx.x, tid = threadIdx.x;
  if (blk < 1024) {  // x convert: 2,097,152 elems, 8/thread
    int i0 = (blk * 256 + tid) * 8;
    f32x4 v0 = *(const f32x4*)(x + i0);
    f32x4 v1 = *(const f32x4*)(x + i0 + 4);
    u32x4 pk;
    pk[0] = (u32)f2bf(v0[0]) | ((u32)f2bf(v0[1]) << 16);
    pk[1] = (u32)f2bf(v0[2]) | ((u32)f2bf(v0[3]) << 16);
    pk[2] = (u32)f2bf(v1[0]) | ((u32)f2bf(v1[1]) << 16);
    pk[3] = (u32)f2bf(v1[2]) | ((u32)f2bf(v1[3]) << 16);
    *(u32x4*)(xb + i0) = pk;
    return;
  }
  if (blk < 1024 + 96 + 64) {  // weight transposes, 64x64 f32 tiles
    int t = blk - 1024;
    const float* W;
    u16* dst;
    int k0, n0, outld, outrow0;
    if (t < 96) {
      int sel = t >> 5, tt = t & 31;
      W = sel == 0 ? Wq : (sel == 1 ? Wk : Wv);
      k0 = (tt >> 3) * 64;
      n0 = (tt & 7) * 64;
      dst = WqkvT;
      outld = 256;
      outrow0 = sel * 512 + n0;
    } else {
      int tt = t - 96;
      W = Wo;
      k0 = (tt >> 3) * 64;
      n0 = (tt & 7) * 64;
      dst = WoT;
      outld = 512;
      outrow0 = n0;
    }
    const int r = tid >> 2, q = tid & 3;
#pragma unroll
    for (int i = 0; i < 4; i++) {
      f32x4 vv = *(const f32x4*)(W + (size_t)(k0 + r) * 512 + n0 + q * 16 + i * 4);
      T[r][q * 16 + i * 4 + 0] = vv[0];
      T[r][q * 16 + i * 4 + 1] = vv[1];
      T[r][q * 16 + i * 4 + 2] = vv[2];
      T[r][q * 16 + i * 4 + 3] = vv[3];
    }
    __syncthreads();
    u16 tmpv[16];
#pragma unroll
    for (int e = 0; e < 16; e++) tmpv[e] = f2bf(T[q * 16 + e][r]);
    u32x4 w0, w1;
#pragma unroll
    for (int j = 0; j < 4; j++) {
      w0[j] = (u32)tmpv[2 * j] | ((u32)tmpv[2 * j + 1] << 16);
      w1[j] = (u32)tmpv[8 + 2 * j] | ((u32)tmpv[9 + 2 * j] << 16);
    }
    u16* dp = dst + (size_t)(outrow0 + r) * outld + k0 + q * 16;
    *(u32x4*)dp = w0;
    *(u32x4*)(dp + 8) = w1;
    return;
  }
  for (int i = tid; i < 1536; i += 256)
    biasQKV[i] = i < 512 ? bq[i] : (i < 1024 ? bk[i - 512] : bv[i - 1024]);
}

// ---------------------------------------------------------------------------
// topk: one wave per row. Threshold-select (interpolation search on u32 keys,
// targeting 32<=count<=64 candidates) + ballot compaction + 64-lane bitonic
// sort by (value desc, index asc) -> exact jax top-32 set with tie-break.
// Output: per row, 32 packed entries (idx<<16 | bf16(tau*w*LOG2E)) sorted by
// (g-bucket=(idx>>2)&3, idx), plus packed bucket starts.
// ---------------------------------------------------------------------------
__global__ __launch_bounds__(256) void topk_kernel(const float* __restrict__ sim,
                                                   const float* __restrict__ tau_raw,
                                                   u32* __restrict__ tpw,
                                                   u32* __restrict__ tstarts) {
  __shared__ u32 keyA[4][64];
  __shared__ u32 idxA[4][64];
  const int tid = threadIdx.x, lane = tid & 63, w = tid >> 6;
  const int row = blockIdx.x * 4 + w;
  const int b = row >> 11, n = row & 2047;
  const float* src = sim + ((size_t)b * 2048 + n) * 2048;

  // keys: monotonic u32 encoding of clamped value; self -> 0 (never selected)
  u32 keys[32];
#pragma unroll
  for (int q = 0; q < 8; q++) {
    f32x4 v = *(const f32x4*)(src + q * 256 + lane * 4);
#pragma unroll
    for (int j = 0; j < 4; j++) {
      int m = (q << 8) + lane * 4 + j;
      float xv = fmaxf(v[j], 0.f);
      keys[q * 4 + j] = (m == n) ? 0u : (__builtin_bit_cast(u32, xv) + 1u);
    }
  }

  // find threshold P with 32 <= #{key >= P} <= 64
  u32 Plo = 1u;           // count(>=1) = 2047 >= 32
  u32 Phi = 0x7F000000u;  // count ~ 0
  u32 P = 0x3F7C0001u;    // key(0.984375): uniform-model guess for rank-48
  int c = 0;
  for (int it = 0; it < 40; ++it) {
    int lc = 0;
#pragma unroll
    for (int e = 0; e < 32; e++) lc += (keys[e] >= P) ? 1 : 0;
#pragma unroll
    for (int off = 1; off < 64; off <<= 1) lc += __shfl_xor(lc, off, 64);
    c = lc;
    if (c >= 32 && c <= 64) break;
    if (c < 32) Phi = P; else Plo = P;
    if (Phi - Plo <= 1) break;  // degenerate (>32-way tie straddle) — unreachable
    long long Pn;
    if (P >= 0x3F000000u && P <= 0x3F800000u) {
      // uniform model: ~4098 key units per unit count in [0.5,1) zone; aim mid-window
      Pn = (long long)P + (long long)(c - 48) * 4098;
    } else {
      Pn = (long long)Plo + (long long)((Phi - Plo) >> 1);
    }
    if (Pn <= (long long)Plo || Pn >= (long long)Phi)
      Pn = (long long)Plo + (long long)((Phi - Plo) >> 1);
    P = (u32)Pn;
  }

  // ballot-compact candidates (key >= P) into per-wave LDS
  u32* kws = keyA[w];
  u32* iws = idxA[w];
  int base = 0;
#pragma unroll
  for (int e = 0; e < 32; e++) {
    bool pred = keys[e] >= P;
    u64 mk = __ballot(pred);
    if (pred) {
      int slot = base + mbcnt64(mk);
      if (slot < 64) {
        kws[slot] = keys[e];
        iws[slot] = (u32)((e >> 2) * 256 + lane * 4 + (e & 3));
      }
    }
    base += __popcll(mk);
  }
  for (int s = base + lane; s < 64; s += 64) {  // pad (sorts last)
    kws[s] = 0u;
    iws[s] = 2047u;
  }

  // 64-lane bitonic, descending by (key, then ascending idx)
  u64 K = ((u64)kws[lane] << 11) | (u64)(2047u - iws[lane]);
#pragma unroll
  for (int k = 2; k <= 64; k <<= 1) {
#pragma unroll
    for (int j = k >> 1; j >= 1; j >>= 1) {
      u64 o = shfl_xor64(K, j);
      bool keepmax = (((lane & k) == 0) == ((lane & j) == 0));
      u64 mx = K > o ? K : o;
      u64 mn = K > o ? o : K;
      K = keepmax ? mx : mn;
    }
  }

  // lanes 0..31 hold the top-32
  u32 key = (u32)(K >> 11);
  int myidx = 2047 - (int)(K & 0x7FFu);
  float myval = __builtin_bit_cast(float, key - 1u);
  float sv = (lane < 32) ? myval : 0.f;
#pragma unroll
  for (int off = 1; off < 64; off <<= 1) sv += __shfl_xor(sv, off, 64);
  float tau = log1pf(__expf(tau_raw[0]));
  float wvv = tau * myval / fmaxf(sv, 1e-8f) * LOG2E;

  int bucket = (myidx >> 2) & 3;
  u64 bm0 = __ballot(lane < 32 && bucket == 0);
  u64 bm1 = __ballot(lane < 32 && bucket == 1);
  u64 bm2 = __ballot(lane < 32 && bucket == 2);
  int c0 = __popcll(bm0), c1 = __popcll(bm1), c2 = __popcll(bm2);
  int key2 = (bucket << 11) | myidx;
  int rank = 0;
  for (int j2 = 0; j2 < 32; j2++) {
    int ok = __shfl(key2, j2, 64);
    rank += (ok < key2) ? 1 : 0;
  }
  if (lane < 32) tpw[(size_t)row * 32 + rank] = ((u32)myidx << 16) | (u32)f2bf(wvv);
  if (lane == 0)
    tstarts[row] = ((u32)c0 << 8) | ((u32)(c0 + c1) << 16) | ((u32)(c0 + c1 + c2) << 24);
}

// ---------------------------------------------------------------------------
// NT GEMM: A [M][K] bf16, Bt [N][K] bf16, 128x128 tile, BK=32, 4 waves.
// MODE 0: scatter bf16 to Q/K/V head-split buffers (Q pre-scaled by QSCALE).
// MODE 1: f32 out [M][N].
// ---------------------------------------------------------------------------
template <int MODE>
__global__ __launch_bounds__(256) void gemm_nt(const u16* __restrict__ A,
                                               const u16* __restrict__ Bt,
                                               const float* __restrict__ bias,
                                               u16* __restrict__ outQ, u16* __restrict__ outK,
                                               u16* __restrict__ outV, float* __restrict__ outF,
                                               int M, int N, int K) {
  __shared__ __align__(16) u16 As[128 * 32];
  __shared__ __align__(16) u16 Bs[128 * 32];

  const int tid = threadIdx.x;
  const int lane = tid & 63;
  const int w = tid >> 6;
  const int g = lane >> 4, c = lane & 15;
  const int wr = (w >> 1) * 64, wc = (w & 1) * 64;
  const int m0 = blockIdx.y * 128, n0 = blockIdx.x * 128;

  f32x4 acc[4][4];
#pragma unroll
  for (int i = 0; i < 4; i++)
#pragma unroll
    for (int j = 0; j < 4; j++) acc[i][j] = f32x4{0.f, 0.f, 0.f, 0.f};

  const int srow = tid >> 1;
  const int shalf = tid & 1;
  const u16* Arow = A + (size_t)(m0 + srow) * K + shalf * 16;
  const u16* Brow = Bt + (size_t)(n0 + srow) * K + shalf * 16;
  char* asbase = (char*)As;
  char* bsbase = (char*)Bs;
  const u32 swz = (u32)((srow & 7) << 4);
  const u32 wb0 = (u32)(srow * 64 + shalf * 32);

  for (int kt = 0; kt < K; kt += 32) {
    __syncthreads();
    {
      u32x4 a0 = *(const u32x4*)(Arow + kt);
      u32x4 a1 = *(const u32x4*)(Arow + kt + 8);
      u32x4 b0 = *(const u32x4*)(Brow + kt);
      u32x4 b1 = *(const u32x4*)(Brow + kt + 8);
      *(u32x4*)(asbase + ((wb0 + 0) ^ swz)) = a0;
      *(u32x4*)(asbase + ((wb0 + 16) ^ swz)) = a1;
      *(u32x4*)(bsbase + ((wb0 + 0) ^ swz)) = b0;
      *(u32x4*)(bsbase + ((wb0 + 16) ^ swz)) = b1;
    }
    __syncthreads();
    u32x4 af[4], bfr[4];
#pragma unroll
    for (int fr = 0; fr < 4; fr++) {
      int row = wr + fr * 16 + c;
      af[fr] = *(const u32x4*)(asbase + ((u32)(row * 64 + g * 16) ^ ((u32)((row & 7) << 4))));
    }
#pragma unroll
    for (int fc = 0; fc < 4; fc++) {
      int row = wc + fc * 16 + c;
      bfr[fc] = *(const u32x4*)(bsbase + ((u32)(row * 64 + g * 16) ^ ((u32)((row & 7) << 4))));
    }
#pragma unroll
    for (int fr = 0; fr < 4; fr++)
#pragma unroll
      for (int fc = 0; fc < 4; fc++) mfma_b16(acc[fr][fc], af[fr], bfr[fc]);
  }
  mfma_fence();
#pragma unroll
  for (int fc = 0; fc < 4; fc++) {
    int gcol = n0 + wc + fc * 16 + c;
    float bvv = bias[gcol];
#pragma unroll
    for (int fr = 0; fr < 4; fr++) {
#pragma unroll
      for (int r = 0; r < 4; r++) {
        int grow = m0 + wr + fr * 16 + 4 * g + r;
        float v = acc[fr][fc][r] + bvv;
        if (MODE == 0) {
          int sel = gcol >> 9, c9 = gcol & 511;
          if (sel == 0) v *= QSCALE;
          int hh = c9 >> 6, dd = c9 & 63;
          int bb = grow >> 11, nn = grow & 2047;
          size_t off2 = ((size_t)(bb * 8 + hh) * 2048 + nn) * 64 + dd;
          u16* dst = sel == 0 ? outQ : (sel == 1 ? outK : outV);
          dst[off2] = f2bf(v);
        } else {
          outF[(size_t)grow * N + gcol] = v;
        }
      }
    }
  }
}

// ---------------------------------------------------------------------------
// transpose V: [BH][N][64] -> [BH][64][N] (bf16)
// ---------------------------------------------------------------------------
__global__ __launch_bounds__(256) void transpose_v(const u16* __restrict__ Vb,
                                                   u16* __restrict__ Vt) {
  __shared__ __align__(16) u16 T[64 * 72];
  const int nt = blockIdx.x, bh = blockIdx.y;
  const int tid = threadIdx.x;
  const int rr = tid >> 2, q = tid & 3;
  {
    const u16* src = Vb + ((size_t)bh * 2048 + nt * 64 + rr) * 64 + q * 16;
    u32x4 a = *(const u32x4*)src;
    u32x4 b = *(const u32x4*)(src + 8);
    *(u32x4*)(&T[rr * 72 + q * 16]) = a;
    *(u32x4*)(&T[rr * 72 + q * 16 + 8]) = b;
  }
  __syncthreads();
  {
    union { u16 s[16]; u32x4 v[2]; } ou;
#pragma unroll
    for (int e = 0; e < 16; e++) ou.s[e] = T[(q * 16 + e) * 72 + rr];
    u16* dst = Vt + ((size_t)bh * 64 + rr) * 2048 + nt * 64 + q * 16;
    *(u32x4*)dst = ou.v[0];
    *(u32x4*)(dst + 8) = ou.v[1];
  }
}

// ---------------------------------------------------------------------------
// flash attention, swapped-QK^T, QBLK=128 (2 q-subtiles per wave), KVBLK=64.
// Double-buffered K/V LDS + register prefetch (1 barrier/tile). Sparse bias
// via g-bucketed per-row lists; defer-max THR=8; exp2-domain softmax.
// Grid: 512 flat, XCD-grouped (bid&7 -> XCD, 4 bh per XCD).
// ---------------------------------------------------------------------------
__global__ __launch_bounds__(256) void attn_kernel(const u16* __restrict__ Qb,
                                                   const u16* __restrict__ Kb,
                                                   const u16* __restrict__ Vt,
                                                   const u32* __restrict__ tpw,
                                                   const u32* __restrict__ tstarts,
                                                   u16* __restrict__ attnout) {
  __shared__ __align__(16) u16 Kd[2][64 * 64];
  __shared__ __align__(16) u16 Vd[2][64 * 64];
  __shared__ __align__(16) u16 Ps[4][2][16 * 64];
  __shared__ u32 pws[128 * 32];
  __shared__ u32 tst[128];

  const int bid = blockIdx.x;
  const int bh = (bid & 7) * 4 + ((bid >> 3) & 3);
  const int qt = bid >> 5;  // 0..15
  const int b = bh >> 3, h = bh & 7;
  const int tid = threadIdx.x, lane = tid & 63, w = tid >> 6;
  const int g = lane >> 4, c = lane & 15;
  const int qbase = qt * 128;

  for (int i = tid; i < 4096; i += 256)
    pws[i] = tpw[((size_t)b * 2048 + qbase) * 32 + i];
  if (tid < 128) tst[tid] = tstarts[b * 2048 + qbase + tid];

  // Q fragments for the two q-subtiles
  u32x4 aq0[2], aq1[2];
#pragma unroll
  for (int s = 0; s < 2; s++) {
    const u16* qptr = Qb + ((size_t)bh * 2048 + qbase + s * 64 + w * 16 + c) * 64 + g * 8;
    aq0[s] = *(const u32x4*)qptr;
    aq1[s] = *(const u32x4*)(qptr + 32);
  }

  float m[2] = {-1e30f, -1e30f}, ssum[2] = {0.f, 0.f};
  f32x4 o[2][4];
#pragma unroll
  for (int s = 0; s < 2; s++)
#pragma unroll
    for (int db = 0; db < 4; db++) o[s][db] = f32x4{0.f, 0.f, 0.f, 0.f};

  const int sr = tid >> 2, sq = tid & 3;
  const u16* ksrc = Kb + ((size_t)bh * 2048 + sr) * 64 + sq * 16;
  const u16* vsrc = Vt + ((size_t)bh * 64 + sr) * 2048 + sq * 16;
  char* ksbase = (char*)&Kd[0][0];
  char* vsbase = (char*)&Vd[0][0];
  const u32 sswz = (u32)((sr & 7) << 4);
  const u32 sb0 = (u32)(sr * 128 + sq * 32);

  // hoisted frag offsets (within one 8KB buffer)
  u32 koff[4][2];
#pragma unroll
  for (int cb = 0; cb < 4; cb++) {
    int row = cb * 16 + c;
    u32 sz = (u32)((row & 7) << 4);
    koff[cb][0] = ((u32)(row * 128 + g * 16)) ^ sz;
    koff[cb][1] = ((u32)(row * 128 + g * 16 + 64)) ^ sz;
  }
  u32 poff2[2], pwoff[4];
  {
    u32 sz = (u32)((c & 7) << 4);
#pragma unroll
    for (int mm = 0; mm < 2; mm++) poff2[mm] = ((u32)(c * 128 + mm * 64 + g * 16)) ^ sz;
#pragma unroll
    for (int cb = 0; cb < 4; cb++) pwoff[cb] = ((u32)(c * 128 + cb * 32 + g * 8)) ^ sz;
  }

  // sparse-bias pointers per sub
  int p[2], pend[2];

  // prologue: stage tile 0 into buf0; load tile 1 into regs
  u32x4 rk0 = *(const u32x4*)(ksrc);
  u32x4 rk1 = *(const u32x4*)(ksrc + 8);
  u32x4 rv0 = *(const u32x4*)(vsrc);
  u32x4 rv1 = *(const u32x4*)(vsrc + 8);
  *(u32x4*)(ksbase + ((sb0 + 0) ^ sswz)) = rk0;
  *(u32x4*)(ksbase + ((sb0 + 16) ^ sswz)) = rk1;
  *(u32x4*)(vsbase + ((sb0 + 0) ^ sswz)) = rv0;
  *(u32x4*)(vsbase + ((sb0 + 16) ^ sswz)) = rv1;
  rk0 = *(const u32x4*)(ksrc + 4096);
  rk1 = *(const u32x4*)(ksrc + 4096 + 8);
  rv0 = *(const u32x4*)(vsrc + 64);
  rv1 = *(const u32x4*)(vsrc + 64 + 8);
  __syncthreads();

#pragma unroll
  for (int s = 0; s < 2; s++) {
    u32 stw = tst[s * 64 + w * 16 + c];
    p[s] = (int)((stw >> (8 * g)) & 255u);
    pend[s] = (g == 3) ? 32 : (int)((stw >> (8 * g + 8)) & 255u);
  }

  u32 curoff = 0;
  for (int t = 0; t < 32; ++t) {
    const int jt = t * 64;
    // write staged tile t+1 into the other buffer
    {
      u32 woff = curoff ^ 8192;
      *(u32x4*)(ksbase + woff + ((sb0 + 0) ^ sswz)) = rk0;
      *(u32x4*)(ksbase + woff + ((sb0 + 16) ^ sswz)) = rk1;
      *(u32x4*)(vsbase + woff + ((sb0 + 0) ^ sswz)) = rv0;
      *(u32x4*)(vsbase + woff + ((sb0 + 16) ^ sswz)) = rv1;
    }
    // issue loads for tile t+2 (clamped; redundant at tail, values unused)
    {
      int jt2 = t < 30 ? (t + 2) * 64 : 1984;
      const u16* kp = ksrc + (size_t)jt2 * 64;
      const u16* vp = vsrc + jt2;
      rk0 = *(const u32x4*)kp;
      rk1 = *(const u32x4*)(kp + 8);
      rv0 = *(const u32x4*)vp;
      rv1 = *(const u32x4*)(vp + 8);
    }

    // S^T = K Q^T for both subs (K frags shared)
    f32x4 sA[4], sB[4];
#pragma unroll
    for (int cb = 0; cb < 4; cb++) {
      u32x4 bk0 = *(const u32x4*)(ksbase + curoff + koff[cb][0]);
      u32x4 bk1 = *(const u32x4*)(ksbase + curoff + koff[cb][1]);
      f32x4 tA = f32x4{0.f, 0.f, 0.f, 0.f};
      f32x4 tB = f32x4{0.f, 0.f, 0.f, 0.f};
      mfma_b16(tA, bk0, aq0[0]);
      mfma_b16(tA, bk1, aq1[0]);
      mfma_b16(tB, bk0, aq0[1]);
      mfma_b16(tB, bk1, aq1[1]);
      sA[cb] = tA;
      sB[cb] = tB;
    }
    mfma_fence();

    // sparse bias + softmax per sub
    const int jtend = jt + 64;
#pragma unroll
    for (int s = 0; s < 2; s++) {
      f32x4* sp = (s == 0) ? sA : sB;
      const int rowl = s * 64 + w * 16 + c;
      int pp = p[s];
      const int pe = pend[s];
      while (pp < pe) {
        u32 e = pws[rowl * 32 + pp];
        int j = (int)(e >> 16);
        if (j >= jtend) break;
        float wv = __builtin_bit_cast(float, e << 16);
        int rel = j - jt - 4 * g;
#pragma unroll
        for (int cb = 0; cb < 4; cb++)
#pragma unroll
          for (int r = 0; r < 4; r++) sp[cb][r] += (rel == cb * 16 + r) ? wv : 0.f;
        pp++;
      }
      p[s] = pp;

      float tm = fmaxf(fmaxf(fmaxf(sp[0][0], sp[0][1]), fmaxf(sp[0][2], sp[0][3])),
                       fmaxf(fmaxf(sp[1][0], sp[1][1]), fmaxf(sp[1][2], sp[1][3])));
      tm = fmaxf(tm, fmaxf(fmaxf(fmaxf(sp[2][0], sp[2][1]), fmaxf(sp[2][2], sp[2][3])),
                           fmaxf(fmaxf(sp[3][0], sp[3][1]), fmaxf(sp[3][2], sp[3][3]))));
      tm = fmaxf(tm, __shfl_xor(tm, 16, 64));
      tm = fmaxf(tm, __shfl_xor(tm, 32, 64));
      if (!__all(tm - m[s] <= 8.f)) {
        float mn = fmaxf(m[s], tm);
        float f = exp2v(m[s] - mn);
        m[s] = mn;
        ssum[s] *= f;
#pragma unroll
        for (int db = 0; db < 4; db++) o[s][db] *= f;
      }
      char* pwb = (char*)&Ps[w][s][0];
      float lsum = 0.f;
#pragma unroll
      for (int cb = 0; cb < 4; cb++) {
        float e0 = exp2v(sp[cb][0] - m[s]);
        float e1 = exp2v(sp[cb][1] - m[s]);
        float e2 = exp2v(sp[cb][2] - m[s]);
        float e3 = exp2v(sp[cb][3] - m[s]);
        lsum += (e0 + e1) + (e2 + e3);
        u32x2 pk;
        pk[0] = cvtpk(e0, e1);
        pk[1] = cvtpk(e2, e3);
        *(u32x2*)(pwb + pwoff[cb]) = pk;
      }
      ssum[s] += lsum;
    }

    // P frags
    char* pwbA = (char*)&Ps[w][0][0];
    char* pwbB = (char*)&Ps[w][1][0];
    u32x4 pf0A = *(const u32x4*)(pwbA + poff2[0]);
    u32x4 pf1A = *(const u32x4*)(pwbA + poff2[1]);
    u32x4 pf0B = *(const u32x4*)(pwbB + poff2[0]);
    u32x4 pf1B = *(const u32x4*)(pwbB + poff2[1]);

    // O^T += V^T P (V frags shared)
#pragma unroll
    for (int db = 0; db < 4; db++) {
      u32x4 bv0 = *(const u32x4*)(vsbase + curoff + koff[db][0]);
      u32x4 bv1 = *(const u32x4*)(vsbase + curoff + koff[db][1]);
      mfma_b16(o[0][db], bv0, pf0A);
      mfma_b16(o[0][db], bv1, pf1A);
      mfma_b16(o[1][db], bv0, pf0B);
      mfma_b16(o[1][db], bv1, pf1B);
    }
    mfma_fence();

    __syncthreads();
    curoff ^= 8192;
  }

#pragma unroll
  for (int s = 0; s < 2; s++) {
    float t = ssum[s];
    t += __shfl_xor(t, 16, 64);
    t += __shfl_xor(t, 32, 64);
    float inv = 1.f / t;
    const int n = qbase + s * 64 + w * 16 + c;
    u16* obase = attnout + ((size_t)b * 2048 + n) * 512 + h * 64 + 4 * g;
#pragma unroll
    for (int db = 0; db < 4; db++) {
      u32x2 st;
      st[0] = cvtpk(o[s][db][0] * inv, o[s][db][1] * inv);
      st[1] = cvtpk(o[s][db][2] * inv, o[s][db][3] * inv);
      *(u32x2*)(obase + db * 16) = st;
    }
  }
}

// ---------------------------------------------------------------------------
extern "C" void kernel_launch(void* const* d_in, const int* in_sizes, int n_in,
                              void* d_out, int out_size, void* d_ws, size_t ws_size,
                              hipStream_t stream) {
  (void)in_sizes; (void)n_in; (void)out_size; (void)ws_size;
  const float* x = (const float*)d_in[0];
  const float* sim = (const float*)d_in[1];
  const float* Wq = (const float*)d_in[2];
  const float* bq = (const float*)d_in[3];
  const float* Wk = (const float*)d_in[4];
  const float* bk = (const float*)d_in[5];
  const float* Wv = (const float*)d_in[6];
  const float* bv = (const float*)d_in[7];
  const float* Wo = (const float*)d_in[8];
  const float* bo = (const float*)d_in[9];
  const float* tau = (const float*)d_in[10];
  float* out = (float*)d_out;

  char* ws = (char*)d_ws;
  size_t off = 0;
  auto alloc = [&](size_t bytes) {
    void* p = ws + off;
    off += (bytes + 255) & ~(size_t)255;
    return p;
  };
  u16* xb = (u16*)alloc((size_t)8192 * 256 * 2);
  u16* WqkvT = (u16*)alloc((size_t)1536 * 256 * 2);
  u16* WoT = (u16*)alloc((size_t)512 * 512 * 2);
  float* biasQKV = (float*)alloc((size_t)1536 * 4);
  u16* Qb = (u16*)alloc((size_t)32 * 2048 * 64 * 2);
  u16* Kb = (u16*)alloc((size_t)32 * 2048 * 64 * 2);
  u16* Vb = (u16*)alloc((size_t)32 * 2048 * 64 * 2);
  u16* Vt = (u16*)alloc((size_t)32 * 2048 * 64 * 2);
  u16* attnout = (u16*)alloc((size_t)8192 * 512 * 2);
  u32* tpw = (u32*)alloc((size_t)8192 * 32 * 4);
  u32* tstarts = (u32*)alloc((size_t)8192 * 4);

  prep_kernel<<<dim3(1185), dim3(256), 0, stream>>>(x, Wq, Wk, Wv, Wo, bq, bk, bv, xb, WqkvT,
                                                    WoT, biasQKV);
  topk_kernel<<<dim3(2048), dim3(256), 0, stream>>>(sim, tau, tpw, tstarts);
  gemm_nt<0><<<dim3(12, 64), dim3(256), 0, stream>>>(xb, WqkvT, biasQKV, Qb, Kb, Vb, nullptr,
                                                     8192, 1536, 256);
  transpose_v<<<dim3(32, 32), dim3(256), 0, stream>>>(Vb, Vt);
  attn_kernel<<<dim3(512), dim3(256), 0, stream>>>(Qb, Kb, Vt, tpw, tstarts, attnout);
  gemm_nt<1><<<dim3(4, 64), dim3(256), 0, stream>>>(attnout, WoT, bo, nullptr, nullptr, nullptr,
                                                    out, 8192, 512, 512);
}

// Round 7
// 250.548 us; speedup vs baseline: 1.0867x; 1.0867x over previous
//
#include <hip/hip_runtime.h>

typedef unsigned int u32;
typedef unsigned short u16;
typedef unsigned long long u64;
typedef float f32x4 __attribute__((ext_vector_type(4)));
typedef u32 u32x4 __attribute__((ext_vector_type(4)));
typedef u32 u32x2 __attribute__((ext_vector_type(2)));

#define DEVINL static __device__ __forceinline__
#define LOG2E 1.44269504088896340736f
#define QSCALE 0.18033688011112042f /* 0.125 * LOG2E */

DEVINL u16 f2bf(float f) {
  u32 u = __builtin_bit_cast(u32, f);
  u32 r = u + 0x7FFFu + ((u >> 16) & 1u);
  return (u16)(r >> 16);
}

DEVINL u32 cvtpk(float lo, float hi) {
  u32 r;
  asm("v_cvt_pk_bf16_f32 %0, %1, %2" : "=v"(r) : "v"(lo), "v"(hi));
  return r;
}
DEVINL float exp2v(float x) {
  float r;
  asm("v_exp_f32 %0, %1" : "=v"(r) : "v"(x));
  return r;
}
DEVINL void mfma_b16(f32x4& c, u32x4 a, u32x4 b) {
  asm volatile("v_mfma_f32_16x16x32_bf16 %0, %1, %2, %0" : "+v"(c) : "v"(a), "v"(b));
}
DEVINL void mfma_fence() { asm volatile("s_nop 7\n\ts_nop 7"); }

DEVINL int mbcnt64(u64 m) {
  return __builtin_amdgcn_mbcnt_hi((u32)(m >> 32), __builtin_amdgcn_mbcnt_lo((u32)m, 0));
}
DEVINL u64 shfl_xor64(u64 v, int m) {
  u32 lo = (u32)v, hi = (u32)(v >> 32);
  lo = __shfl_xor(lo, m, 64);
  hi = __shfl_xor(hi, m, 64);
  return ((u64)hi << 32) | lo;
}

// ---------------------------------------------------------------------------
// prep: x -> bf16; tiled transpose of Wq/Wk/Wv -> WqkvT [1536][256] bf16 and
// Wo -> WoT [512][512] bf16; concat qkv bias. Grid = 1024 + 96 + 64 + 1.
// ---------------------------------------------------------------------------
__global__ __launch_bounds__(256) void prep_kernel(
    const float* __restrict__ x, const float* __restrict__ Wq, const float* __restrict__ Wk,
    const float* __restrict__ Wv, const float* __restrict__ Wo, const float* __restrict__ bq,
    const float* __restrict__ bk, const float* __restrict__ bv, u16* __restrict__ xb,
    u16* __restrict__ WqkvT, u16* __restrict__ WoT, float* __restrict__ biasQKV) {
  __shared__ float T[64][65];
  const int blk = blockIdx.x, tid = threadIdx.x;
  if (blk < 1024) {  // x convert: 2,097,152 elems, 8/thread
    int i0 = (blk * 256 + tid) * 8;
    f32x4 v0 = *(const f32x4*)(x + i0);
    f32x4 v1 = *(const f32x4*)(x + i0 + 4);
    u32x4 pk;
    pk[0] = (u32)f2bf(v0[0]) | ((u32)f2bf(v0[1]) << 16);
    pk[1] = (u32)f2bf(v0[2]) | ((u32)f2bf(v0[3]) << 16);
    pk[2] = (u32)f2bf(v1[0]) | ((u32)f2bf(v1[1]) << 16);
    pk[3] = (u32)f2bf(v1[2]) | ((u32)f2bf(v1[3]) << 16);
    *(u32x4*)(xb + i0) = pk;
    return;
  }
  if (blk < 1024 + 96 + 64) {  // weight transposes, 64x64 f32 tiles
    int t = blk - 1024;
    const float* W;
    u16* dst;
    int k0, n0, outld, outrow0;
    if (t < 96) {
      int sel = t >> 5, tt = t & 31;
      W = sel == 0 ? Wq : (sel == 1 ? Wk : Wv);
      k0 = (tt >> 3) * 64;
      n0 = (tt & 7) * 64;
      dst = WqkvT;
      outld = 256;
      outrow0 = sel * 512 + n0;
    } else {
      int tt = t - 96;
      W = Wo;
      k0 = (tt >> 3) * 64;
      n0 = (tt & 7) * 64;
      dst = WoT;
      outld = 512;
      outrow0 = n0;
    }
    const int r = tid >> 2, q = tid & 3;
#pragma unroll
    for (int i = 0; i < 4; i++) {
      f32x4 vv = *(const f32x4*)(W + (size_t)(k0 + r) * 512 + n0 + q * 16 + i * 4);
      T[r][q * 16 + i * 4 + 0] = vv[0];
      T[r][q * 16 + i * 4 + 1] = vv[1];
      T[r][q * 16 + i * 4 + 2] = vv[2];
      T[r][q * 16 + i * 4 + 3] = vv[3];
    }
    __syncthreads();
    u16 tmpv[16];
#pragma unroll
    for (int e = 0; e < 16; e++) tmpv[e] = f2bf(T[q * 16 + e][r]);
    u32x4 w0, w1;
#pragma unroll
    for (int j = 0; j < 4; j++) {
      w0[j] = (u32)tmpv[2 * j] | ((u32)tmpv[2 * j + 1] << 16);
      w1[j] = (u32)tmpv[8 + 2 * j] | ((u32)tmpv[9 + 2 * j] << 16);
    }
    u16* dp = dst + (size_t)(outrow0 + r) * outld + k0 + q * 16;
    *(u32x4*)dp = w0;
    *(u32x4*)(dp + 8) = w1;
    return;
  }
  for (int i = tid; i < 1536; i += 256)
    biasQKV[i] = i < 512 ? bq[i] : (i < 1024 ? bk[i - 512] : bv[i - 1024]);
}

// ---------------------------------------------------------------------------
// topk: one wave per row. Threshold-select (interpolation search on u32 keys,
// targeting 32<=count<=64 candidates) + ballot compaction + 64-lane bitonic
// sort by (value desc, index asc) -> exact jax top-32 set with tie-break.
// Output: per row, 32 packed entries (idx<<16 | bf16(tau*w*LOG2E)) sorted by
// (g-bucket=(idx>>2)&3, idx), plus packed bucket starts.
// ---------------------------------------------------------------------------
__global__ __launch_bounds__(256) void topk_kernel(const float* __restrict__ sim,
                                                   const float* __restrict__ tau_raw,
                                                   u32* __restrict__ tpw,
                                                   u32* __restrict__ tstarts) {
  __shared__ u32 keyA[4][64];
  __shared__ u32 idxA[4][64];
  const int tid = threadIdx.x, lane = tid & 63, w = tid >> 6;
  const int row = blockIdx.x * 4 + w;
  const int b = row >> 11, n = row & 2047;
  const float* src = sim + ((size_t)b * 2048 + n) * 2048;

  // keys: monotonic u32 encoding of clamped value; self -> 0 (never selected)
  u32 keys[32];
#pragma unroll
  for (int q = 0; q < 8; q++) {
    f32x4 v = *(const f32x4*)(src + q * 256 + lane * 4);
#pragma unroll
    for (int j = 0; j < 4; j++) {
      int m = (q << 8) + lane * 4 + j;
      float xv = fmaxf(v[j], 0.f);
      keys[q * 4 + j] = (m == n) ? 0u : (__builtin_bit_cast(u32, xv) + 1u);
    }
  }

  // find threshold P with 32 <= #{key >= P} <= 64
  u32 Plo = 1u;           // count(>=1) = 2047 >= 32
  u32 Phi = 0x7F000000u;  // count ~ 0
  u32 P = 0x3F7C0001u;    // key(0.984375): uniform-model guess for rank-48
  int c = 0;
  for (int it = 0; it < 40; ++it) {
    int lc = 0;
#pragma unroll
    for (int e = 0; e < 32; e++) lc += (keys[e] >= P) ? 1 : 0;
#pragma unroll
    for (int off = 1; off < 64; off <<= 1) lc += __shfl_xor(lc, off, 64);
    c = lc;
    if (c >= 32 && c <= 64) break;
    if (c < 32) Phi = P; else Plo = P;
    if (Phi - Plo <= 1) break;  // degenerate (>32-way tie straddle) — unreachable
    long long Pn;
    if (P >= 0x3F000000u && P <= 0x3F800000u) {
      // uniform model: ~4098 key units per unit count in [0.5,1) zone; aim mid-window
      Pn = (long long)P + (long long)(c - 48) * 4098;
    } else {
      Pn = (long long)Plo + (long long)((Phi - Plo) >> 1);
    }
    if (Pn <= (long long)Plo || Pn >= (long long)Phi)
      Pn = (long long)Plo + (long long)((Phi - Plo) >> 1);
    P = (u32)Pn;
  }

  // ballot-compact candidates (key >= P) into per-wave LDS
  u32* kws = keyA[w];
  u32* iws = idxA[w];
  int base = 0;
#pragma unroll
  for (int e = 0; e < 32; e++) {
    bool pred = keys[e] >= P;
    u64 mk = __ballot(pred);
    if (pred) {
      int slot = base + mbcnt64(mk);
      if (slot < 64) {
        kws[slot] = keys[e];
        iws[slot] = (u32)((e >> 2) * 256 + lane * 4 + (e & 3));
      }
    }
    base += __popcll(mk);
  }
  for (int s = base + lane; s < 64; s += 64) {  // pad (sorts last)
    kws[s] = 0u;
    iws[s] = 2047u;
  }

  // 64-lane bitonic, descending by (key, then ascending idx)
  u64 K = ((u64)kws[lane] << 11) | (u64)(2047u - iws[lane]);
#pragma unroll
  for (int k = 2; k <= 64; k <<= 1) {
#pragma unroll
    for (int j = k >> 1; j >= 1; j >>= 1) {
      u64 o = shfl_xor64(K, j);
      bool keepmax = (((lane & k) == 0) == ((lane & j) == 0));
      u64 mx = K > o ? K : o;
      u64 mn = K > o ? o : K;
      K = keepmax ? mx : mn;
    }
  }

  // lanes 0..31 hold the top-32
  u32 key = (u32)(K >> 11);
  int myidx = 2047 - (int)(K & 0x7FFu);
  float myval = __builtin_bit_cast(float, key - 1u);
  float sv = (lane < 32) ? myval : 0.f;
#pragma unroll
  for (int off = 1; off < 64; off <<= 1) sv += __shfl_xor(sv, off, 64);
  float tau = log1pf(__expf(tau_raw[0]));
  float wvv = tau * myval / fmaxf(sv, 1e-8f) * LOG2E;

  int bucket = (myidx >> 2) & 3;
  u64 bm0 = __ballot(lane < 32 && bucket == 0);
  u64 bm1 = __ballot(lane < 32 && bucket == 1);
  u64 bm2 = __ballot(lane < 32 && bucket == 2);
  int c0 = __popcll(bm0), c1 = __popcll(bm1), c2 = __popcll(bm2);
  int key2 = (bucket << 11) | myidx;
  int rank = 0;
  for (int j2 = 0; j2 < 32; j2++) {
    int ok = __shfl(key2, j2, 64);
    rank += (ok < key2) ? 1 : 0;
  }
  if (lane < 32) tpw[(size_t)row * 32 + rank] = ((u32)myidx << 16) | (u32)f2bf(wvv);
  if (lane == 0)
    tstarts[row] = ((u32)c0 << 8) | ((u32)(c0 + c1) << 16) | ((u32)(c0 + c1 + c2) << 24);
}

// ---------------------------------------------------------------------------
// NT GEMM: A [M][K] bf16, Bt [N][K] bf16, 128x128 tile, BK=32, 4 waves.
// MODE 0: scatter bf16 to Q/K/V head-split buffers (Q pre-scaled by QSCALE).
// MODE 1: f32 out [M][N].
// ---------------------------------------------------------------------------
template <int MODE>
__global__ __launch_bounds__(256) void gemm_nt(const u16* __restrict__ A,
                                               const u16* __restrict__ Bt,
                                               const float* __restrict__ bias,
                                               u16* __restrict__ outQ, u16* __restrict__ outK,
                                               u16* __restrict__ outV, float* __restrict__ outF,
                                               int M, int N, int K) {
  __shared__ __align__(16) u16 As[128 * 32];
  __shared__ __align__(16) u16 Bs[128 * 32];

  const int tid = threadIdx.x;
  const int lane = tid & 63;
  const int w = tid >> 6;
  const int g = lane >> 4, c = lane & 15;
  const int wr = (w >> 1) * 64, wc = (w & 1) * 64;
  const int m0 = blockIdx.y * 128, n0 = blockIdx.x * 128;

  f32x4 acc[4][4];
#pragma unroll
  for (int i = 0; i < 4; i++)
#pragma unroll
    for (int j = 0; j < 4; j++) acc[i][j] = f32x4{0.f, 0.f, 0.f, 0.f};

  const int srow = tid >> 1;
  const int shalf = tid & 1;
  const u16* Arow = A + (size_t)(m0 + srow) * K + shalf * 16;
  const u16* Brow = Bt + (size_t)(n0 + srow) * K + shalf * 16;
  char* asbase = (char*)As;
  char* bsbase = (char*)Bs;
  const u32 swz = (u32)((srow & 7) << 4);
  const u32 wb0 = (u32)(srow * 64 + shalf * 32);

  for (int kt = 0; kt < K; kt += 32) {
    __syncthreads();
    {
      u32x4 a0 = *(const u32x4*)(Arow + kt);
      u32x4 a1 = *(const u32x4*)(Arow + kt + 8);
      u32x4 b0 = *(const u32x4*)(Brow + kt);
      u32x4 b1 = *(const u32x4*)(Brow + kt + 8);
      *(u32x4*)(asbase + ((wb0 + 0) ^ swz)) = a0;
      *(u32x4*)(asbase + ((wb0 + 16) ^ swz)) = a1;
      *(u32x4*)(bsbase + ((wb0 + 0) ^ swz)) = b0;
      *(u32x4*)(bsbase + ((wb0 + 16) ^ swz)) = b1;
    }
    __syncthreads();
    u32x4 af[4], bfr[4];
#pragma unroll
    for (int fr = 0; fr < 4; fr++) {
      int row = wr + fr * 16 + c;
      af[fr] = *(const u32x4*)(asbase + ((u32)(row * 64 + g * 16) ^ ((u32)((row & 7) << 4))));
    }
#pragma unroll
    for (int fc = 0; fc < 4; fc++) {
      int row = wc + fc * 16 + c;
      bfr[fc] = *(const u32x4*)(bsbase + ((u32)(row * 64 + g * 16) ^ ((u32)((row & 7) << 4))));
    }
#pragma unroll
    for (int fr = 0; fr < 4; fr++)
#pragma unroll
      for (int fc = 0; fc < 4; fc++) mfma_b16(acc[fr][fc], af[fr], bfr[fc]);
  }
  mfma_fence();
#pragma unroll
  for (int fc = 0; fc < 4; fc++) {
    int gcol = n0 + wc + fc * 16 + c;
    float bvv = bias[gcol];
#pragma unroll
    for (int fr = 0; fr < 4; fr++) {
#pragma unroll
      for (int r = 0; r < 4; r++) {
        int grow = m0 + wr + fr * 16 + 4 * g + r;
        float v = acc[fr][fc][r] + bvv;
        if (MODE == 0) {
          int sel = gcol >> 9, c9 = gcol & 511;
          if (sel == 0) v *= QSCALE;
          int hh = c9 >> 6, dd = c9 & 63;
          int bb = grow >> 11, nn = grow & 2047;
          size_t off2 = ((size_t)(bb * 8 + hh) * 2048 + nn) * 64 + dd;
          u16* dst = sel == 0 ? outQ : (sel == 1 ? outK : outV);
          dst[off2] = f2bf(v);
        } else {
          outF[(size_t)grow * N + gcol] = v;
        }
      }
    }
  }
}

// ---------------------------------------------------------------------------
// transpose V: [BH][N][64] -> [BH][64][N] (bf16)
// ---------------------------------------------------------------------------
__global__ __launch_bounds__(256) void transpose_v(const u16* __restrict__ Vb,
                                                   u16* __restrict__ Vt) {
  __shared__ __align__(16) u16 T[64 * 72];
  const int nt = blockIdx.x, bh = blockIdx.y;
  const int tid = threadIdx.x;
  const int rr = tid >> 2, q = tid & 3;
  {
    const u16* src = Vb + ((size_t)bh * 2048 + nt * 64 + rr) * 64 + q * 16;
    u32x4 a = *(const u32x4*)src;
    u32x4 b = *(const u32x4*)(src + 8);
    *(u32x4*)(&T[rr * 72 + q * 16]) = a;
    *(u32x4*)(&T[rr * 72 + q * 16 + 8]) = b;
  }
  __syncthreads();
  {
    union { u16 s[16]; u32x4 v[2]; } ou;
#pragma unroll
    for (int e = 0; e < 16; e++) ou.s[e] = T[(q * 16 + e) * 72 + rr];
    u16* dst = Vt + ((size_t)bh * 64 + rr) * 2048 + nt * 64 + q * 16;
    *(u32x4*)dst = ou.v[0];
    *(u32x4*)(dst + 8) = ou.v[1];
  }
}

// ---------------------------------------------------------------------------
// flash attention, swapped-QK^T (S^T = mfma(K,Q)), QBLK=64, KVBLK=64.
// Single-buffered K/V LDS, 2 barriers/tile, issue-early global prefetch of
// the next tile (latency hides under compute). Sparse bias read directly
// from global with one-ahead register prefetch (no pws/tst LDS). setprio
// around MFMA clusters. Defer-max THR=8; exp2-domain softmax (Q pre-scaled).
// LDS = 24.5 KB/block. Grid: 1024 flat, XCD-grouped.
// ---------------------------------------------------------------------------
__global__ __launch_bounds__(256) void attn_kernel(const u16* __restrict__ Qb,
                                                   const u16* __restrict__ Kb,
                                                   const u16* __restrict__ Vt,
                                                   const u32* __restrict__ tpw,
                                                   const u32* __restrict__ tstarts,
                                                   u16* __restrict__ attnout) {
  __shared__ __align__(16) u16 Ks[64 * 64];
  __shared__ __align__(16) u16 Vs[64 * 64];
  __shared__ __align__(16) u16 Ps[4][16 * 64];

  const int bid = blockIdx.x;
  const int bh = (bid & 7) * 4 + ((bid >> 3) & 3);
  const int qt = bid >> 5;
  const int b = bh >> 3, h = bh & 7;
  const int tid = threadIdx.x, lane = tid & 63, w = tid >> 6;
  const int g = lane >> 4, c = lane & 15;
  const int qbase = qt * 64;
  const int rowl = w * 16 + c;

  // Q fragments (Q pre-scaled by 0.125*LOG2E at projection)
  const u16* qptr = Qb + ((size_t)bh * 2048 + qbase + rowl) * 64 + g * 8;
  u32x4 aq0 = *(const u32x4*)qptr;
  u32x4 aq1 = *(const u32x4*)(qptr + 32);

  // sparse-bias list: direct global reads, one-ahead prefetch
  const u32* tpwrow = tpw + ((size_t)b * 2048 + qbase + rowl) * 32;
  u32 stw = tstarts[b * 2048 + qbase + rowl];
  int p = (int)((stw >> (8 * g)) & 255u);
  const int pend = (g == 3) ? 32 : (int)((stw >> (8 * g + 8)) & 255u);
  u32 nextE = (p < pend) ? tpwrow[p] : 0xFFFF0000u;  // j=65535 sentinel

  float m = -1e30f, ssum = 0.f;
  f32x4 o[4];
#pragma unroll
  for (int db = 0; db < 4; db++) o[db] = f32x4{0.f, 0.f, 0.f, 0.f};

  const int sr = tid >> 2, sq = tid & 3;
  const u16* ksrc = Kb + ((size_t)bh * 2048 + sr) * 64 + sq * 16;
  const u16* vsrc = Vt + ((size_t)bh * 64 + sr) * 2048 + sq * 16;
  char* ksb = (char*)Ks;
  char* vsb = (char*)Vs;
  char* pwb = (char*)&Ps[w][0];
  const u32 sswz = (u32)((sr & 7) << 4);
  const u32 sb0 = (u32)(sr * 128 + sq * 32);

  // hoisted LDS frag offsets
  u32 koff[4][2], poff2[2], pwoff[4];
#pragma unroll
  for (int cb = 0; cb < 4; cb++) {
    int row = cb * 16 + c;
    u32 sz = (u32)((row & 7) << 4);
    koff[cb][0] = ((u32)(row * 128 + g * 16)) ^ sz;
    koff[cb][1] = ((u32)(row * 128 + g * 16 + 64)) ^ sz;
  }
  {
    u32 sz = (u32)((c & 7) << 4);
#pragma unroll
    for (int mm = 0; mm < 2; mm++) poff2[mm] = ((u32)(c * 128 + mm * 64 + g * 16)) ^ sz;
#pragma unroll
    for (int cb = 0; cb < 4; cb++) pwoff[cb] = ((u32)(c * 128 + cb * 32 + g * 8)) ^ sz;
  }

  // prologue: load tile 0 into regs
  u32x4 rk0 = *(const u32x4*)ksrc;
  u32x4 rk1 = *(const u32x4*)(ksrc + 8);
  u32x4 rv0 = *(const u32x4*)vsrc;
  u32x4 rv1 = *(const u32x4*)(vsrc + 8);

  for (int t = 0; t < 32; ++t) {
    const int jt = t * 64;
    __syncthreads();  // previous tile's readers done
    *(u32x4*)(ksb + ((sb0 + 0) ^ sswz)) = rk0;
    *(u32x4*)(ksb + ((sb0 + 16) ^ sswz)) = rk1;
    *(u32x4*)(vsb + ((sb0 + 0) ^ sswz)) = rv0;
    *(u32x4*)(vsb + ((sb0 + 16) ^ sswz)) = rv1;
    __syncthreads();  // tile t staged

    // issue next-tile loads now; latency hides under this tile's compute
    {
      int jt2 = t < 31 ? jt + 64 : 1984;
      const u16* kp = ksrc + (size_t)jt2 * 64;
      const u16* vp = vsrc + jt2;
      rk0 = *(const u32x4*)kp;
      rk1 = *(const u32x4*)(kp + 8);
      rv0 = *(const u32x4*)vp;
      rv1 = *(const u32x4*)(vp + 8);
    }

    // S^T = K Q^T: lane holds S[kv=jt+16cb+4g+r][q=rowl]
    __builtin_amdgcn_s_setprio(1);
    f32x4 s[4];
#pragma unroll
    for (int cb = 0; cb < 4; cb++) {
      u32x4 bk0 = *(const u32x4*)(ksb + koff[cb][0]);
      u32x4 bk1 = *(const u32x4*)(ksb + koff[cb][1]);
      f32x4 tacc = f32x4{0.f, 0.f, 0.f, 0.f};
      mfma_b16(tacc, bk0, aq0);
      mfma_b16(tacc, bk1, aq1);
      s[cb] = tacc;
    }
    __builtin_amdgcn_s_setprio(0);
    mfma_fence();

    // sparse bias (this lane's g-bucket only), from global with prefetch
    const int jtend = jt + 64;
    while ((int)(nextE >> 16) < jtend) {
      float wv = __builtin_bit_cast(float, nextE << 16);
      int rel = (int)(nextE >> 16) - jt - 4 * g;
#pragma unroll
      for (int cb = 0; cb < 4; cb++)
#pragma unroll
        for (int r = 0; r < 4; r++) s[cb][r] += (rel == cb * 16 + r) ? wv : 0.f;
      p++;
      nextE = (p < pend) ? tpwrow[p] : 0xFFFF0000u;
    }

    // online softmax (exp2 domain), defer-max THR=8
    float tm = fmaxf(fmaxf(fmaxf(s[0][0], s[0][1]), fmaxf(s[0][2], s[0][3])),
                     fmaxf(fmaxf(s[1][0], s[1][1]), fmaxf(s[1][2], s[1][3])));
    tm = fmaxf(tm, fmaxf(fmaxf(fmaxf(s[2][0], s[2][1]), fmaxf(s[2][2], s[2][3])),
                         fmaxf(fmaxf(s[3][0], s[3][1]), fmaxf(s[3][2], s[3][3]))));
    tm = fmaxf(tm, __shfl_xor(tm, 16, 64));
    tm = fmaxf(tm, __shfl_xor(tm, 32, 64));
    if (!__all(tm - m <= 8.f)) {
      float mn = fmaxf(m, tm);
      float f = exp2v(m - mn);
      m = mn;
      ssum *= f;
#pragma unroll
      for (int db = 0; db < 4; db++) o[db] *= f;
    }
    float lsum = 0.f;
#pragma unroll
    for (int cb = 0; cb < 4; cb++) {
      float e0 = exp2v(s[cb][0] - m);
      float e1 = exp2v(s[cb][1] - m);
      float e2 = exp2v(s[cb][2] - m);
      float e3 = exp2v(s[cb][3] - m);
      lsum += (e0 + e1) + (e2 + e3);
      u32x2 pk;
      pk[0] = cvtpk(e0, e1);
      pk[1] = cvtpk(e2, e3);
      *(u32x2*)(pwb + pwoff[cb]) = pk;
    }
    ssum += lsum;

    // O^T += V^T P : o[db] cols q=c, rows d=db*16+4g+r
    u32x4 pf0 = *(const u32x4*)(pwb + poff2[0]);
    u32x4 pf1 = *(const u32x4*)(pwb + poff2[1]);
    __builtin_amdgcn_s_setprio(1);
#pragma unroll
    for (int db = 0; db < 4; db++) {
      u32x4 bv0 = *(const u32x4*)(vsb + koff[db][0]);
      u32x4 bv1 = *(const u32x4*)(vsb + koff[db][1]);
      mfma_b16(o[db], bv0, pf0);
      mfma_b16(o[db], bv1, pf1);
    }
    __builtin_amdgcn_s_setprio(0);
    // no fence: o[] not VALU-read for >=60 cycles (next tile's QK+bias first)
  }
  mfma_fence();

  ssum += __shfl_xor(ssum, 16, 64);
  ssum += __shfl_xor(ssum, 32, 64);
  float inv = 1.f / ssum;
  const int n = qbase + rowl;
  u16* obase = attnout + ((size_t)b * 2048 + n) * 512 + h * 64 + 4 * g;
#pragma unroll
  for (int db = 0; db < 4; db++) {
    u32x2 st;
    st[0] = cvtpk(o[db][0] * inv, o[db][1] * inv);
    st[1] = cvtpk(o[db][2] * inv, o[db][3] * inv);
    *(u32x2*)(obase + db * 16) = st;
  }
}

// ---------------------------------------------------------------------------
extern "C" void kernel_launch(void* const* d_in, const int* in_sizes, int n_in,
                              void* d_out, int out_size, void* d_ws, size_t ws_size,
                              hipStream_t stream) {
  (void)in_sizes; (void)n_in; (void)out_size; (void)ws_size;
  const float* x = (const float*)d_in[0];
  const float* sim = (const float*)d_in[1];
  const float* Wq = (const float*)d_in[2];
  const float* bq = (const float*)d_in[3];
  const float* Wk = (const float*)d_in[4];
  const float* bk = (const float*)d_in[5];
  const float* Wv = (const float*)d_in[6];
  const float* bv = (const float*)d_in[7];
  const float* Wo = (const float*)d_in[8];
  const float* bo = (const float*)d_in[9];
  const float* tau = (const float*)d_in[10];
  float* out = (float*)d_out;

  char* ws = (char*)d_ws;
  size_t off = 0;
  auto alloc = [&](size_t bytes) {
    void* p = ws + off;
    off += (bytes + 255) & ~(size_t)255;
    return p;
  };
  u16* xb = (u16*)alloc((size_t)8192 * 256 * 2);
  u16* WqkvT = (u16*)alloc((size_t)1536 * 256 * 2);
  u16* WoT = (u16*)alloc((size_t)512 * 512 * 2);
  float* biasQKV = (float*)alloc((size_t)1536 * 4);
  u16* Qb = (u16*)alloc((size_t)32 * 2048 * 64 * 2);
  u16* Kb = (u16*)alloc((size_t)32 * 2048 * 64 * 2);
  u16* Vb = (u16*)alloc((size_t)32 * 2048 * 64 * 2);
  u16* Vt = (u16*)alloc((size_t)32 * 2048 * 64 * 2);
  u16* attnout = (u16*)alloc((size_t)8192 * 512 * 2);
  u32* tpw = (u32*)alloc((size_t)8192 * 32 * 4);
  u32* tstarts = (u32*)alloc((size_t)8192 * 4);

  prep_kernel<<<dim3(1185), dim3(256), 0, stream>>>(x, Wq, Wk, Wv, Wo, bq, bk, bv, xb, WqkvT,
                                                    WoT, biasQKV);
  topk_kernel<<<dim3(2048), dim3(256), 0, stream>>>(sim, tau, tpw, tstarts);
  gemm_nt<0><<<dim3(12, 64), dim3(256), 0, stream>>>(xb, WqkvT, biasQKV, Qb, Kb, Vb, nullptr,
                                                     8192, 1536, 256);
  transpose_v<<<dim3(32, 32), dim3(256), 0, stream>>>(Vb, Vt);
  attn_kernel<<<dim3(1024), dim3(256), 0, stream>>>(Qb, Kb, Vt, tpw, tstarts, attnout);
  gemm_nt<1><<<dim3(4, 64), dim3(256), 0, stream>>>(attnout, WoT, bo, nullptr, nullptr, nullptr,
                                                    out, 8192, 512, 512);
}